// Round 10
// baseline (124.974 us; speedup 1.0000x reference)
//
#include <hip/hip_runtime.h>

#define T_GT 64
#define KP 2            // priors per thread
#define TPB 256
#define NPRB (TPB * KP) // priors per block

typedef unsigned int u32;
typedef unsigned long long u64;
typedef unsigned char u8;

// ---------------------------------------------------------------------------
// Single fused kernel, fence-free last-block finisher, hybrid store path.
//
// Compute (round-7 core): thread = (b, KP consecutive priors).
//  Phase 1: exact overlap screen (inter>0 <=> 4 strict compares). Mask bit
//    k==t; ctz-ascending visit preserves numpy first-index tie-break.
//  Phase 2: full __f*_rn IoU for overlapping pairs only (~5%):
//    match: pack (q<<32)|(63-t) max; best_prior: LDS atomicMax of
//    (q<<32)|(~p) per wave per t. Defaults == numpy argmax over zeros.
//
// Store discipline (round-9 post-mortem: write-through everything tripled
// WRITE_SIZE to 114 MB and made the kernel write-bound):
//  - A row can be overridden only if it is the FINAL winner for some t,
//    and the final winner is always some block's LOCAL winner. So only the
//    <=64 local-winner rows per block are contended.
//  - Bulk rows: plain cached coalesced stores (single writer, no hazard).
//  - Local-winner rows + part[]: relaxed AGENT stores (write-through LLC,
//    nothing dirty in per-XCD L2 for contended lines).
//  - release: s_waitcnt vmcnt(0) -> __syncthreads -> one relaxed AGENT
//    ticket per block; ticket NG-1 becomes the finisher (no spinning, no
//    device-scope fences — round-8 post-mortem: per-block wbl2 ~ +200 µs).
//  - Finisher AGENT-loads partials, reduces, applies matches[best_prior[t]]
//    = t (ascending scan == numpy last-wins) with AGENT stores; LLC orders
//    them after the owners' AGENT stores.
// ---------------------------------------------------------------------------
__global__ void __launch_bounds__(256)
fused_all(const float4* __restrict__ priors,
          const float4* __restrict__ gt_boxes,
          const int* __restrict__ gt_labels,
          u64* __restrict__ part,        // (B, NG, 64) block partials
          u32* __restrict__ cnt,         // (B) ticket counters, pre-zeroed
          float* __restrict__ out_loc,   // (B, P, 4)
          float* __restrict__ out_lbl,   // (B, P) as float
          int P, int NG) {
    __shared__ float4 s_gt[T_GT];
    __shared__ float  s_ga[T_GT];
    __shared__ int    s_lbl[T_GT];
    __shared__ u64    s_best[4][T_GT];
    __shared__ u32    s_p[T_GT];
    __shared__ u8     s_skip[NPRB];
    __shared__ u8     s_info[NPRB];
    __shared__ u32    s_rank;

    const int tid  = threadIdx.x;
    const int lane = tid & 63;
    const int wv   = tid >> 6;
    const int b    = blockIdx.y;
    const int tb   = blockIdx.x * TPB + tid;
    const int pbase = blockIdx.x * NPRB;

    if (tid < T_GT) {
        const float4 gb = gt_boxes[b * T_GT + tid];
        s_gt[tid]  = gb;
        s_ga[tid]  = __fmul_rn(__fsub_rn(gb.z, gb.x), __fsub_rn(gb.w, gb.y));
        s_lbl[tid] = gt_labels[b * T_GT + tid];
    }
    s_best[wv][lane] = (u64)0xFFFFFFFFu;   // {q=+0.0, p=0} default
    #pragma unroll
    for (int j = 0; j < KP; ++j) s_skip[tid * KP + j] = 0;
    __syncthreads();

    // load KP consecutive priors; precompute xyxy + area (ref op order)
    float px0[KP], py0[KP], px1[KP], py1[KP], pa[KP];
    float4 prr[KP];
    u32 pc[KP];
    #pragma unroll
    for (int j = 0; j < KP; ++j) {
        const int p = min(tb * KP + j, P - 1);  // clamp: dup of P-1 harmless
        pc[j] = (u32)p;
        const float4 pr = priors[p];
        prr[j] = pr;
        px0[j] = __fsub_rn(pr.x, __fmul_rn(0.5f, pr.z));
        py0[j] = __fsub_rn(pr.y, __fmul_rn(0.5f, pr.w));
        px1[j] = __fadd_rn(pr.x, __fmul_rn(0.5f, pr.z));
        py1[j] = __fadd_rn(pr.y, __fmul_rn(0.5f, pr.w));
        pa[j]  = __fmul_rn(__fsub_rn(px1[j], px0[j]), __fsub_rn(py1[j], py0[j]));
    }

    // ---- phase 1: overlap masks (t descending -> bit k == t) ----
    u32 mhi[KP], mlo[KP];
    #pragma unroll
    for (int j = 0; j < KP; ++j) { mhi[j] = 0; mlo[j] = 0; }

    #pragma unroll 8
    for (int t = 63; t >= 32; --t) {
        const float4 gb = s_gt[t];
        #pragma unroll
        for (int j = 0; j < KP; ++j) {
            const bool ov = (gb.z > px0[j]) & (px1[j] > gb.x) &
                            (gb.w > py0[j]) & (py1[j] > gb.y);
            mhi[j] = mhi[j] + mhi[j] + (ov ? 1u : 0u);
        }
    }
    #pragma unroll 8
    for (int t = 31; t >= 0; --t) {
        const float4 gb = s_gt[t];
        #pragma unroll
        for (int j = 0; j < KP; ++j) {
            const bool ov = (gb.z > px0[j]) & (px1[j] > gb.x) &
                            (gb.w > py0[j]) & (py1[j] > gb.y);
            mlo[j] = mlo[j] + mlo[j] + (ov ? 1u : 0u);
        }
    }

    // ---- phase 2: evaluate candidates only ----
    u64 mbest[KP];
    #pragma unroll
    for (int j = 0; j < KP; ++j) mbest[j] = 63u;   // {q=0, rt=63} == t 0

    #pragma unroll
    for (int j = 0; j < KP; ++j) {
        #pragma unroll
        for (int half = 0; half < 2; ++half) {
            u32 mask = half ? mhi[j] : mlo[j];
            const int tbase = half ? 32 : 0;
            while (mask) {                        // ascending t per lane
                const int t = tbase + __builtin_ctz(mask);
                mask &= mask - 1;
                const float4 gb  = s_gt[t];
                const float  gar = s_ga[t];
                const float ltx = fmaxf(gb.x, px0[j]);
                const float lty = fmaxf(gb.y, py0[j]);
                const float rbx = fminf(gb.z, px1[j]);
                const float rby = fminf(gb.w, py1[j]);
                const float wx = fmaxf(__fsub_rn(rbx, ltx), 0.0f);
                const float wy = fmaxf(__fsub_rn(rby, lty), 0.0f);
                const float inter = __fmul_rn(wx, wy);
                const float uni = __fsub_rn(__fadd_rn(gar, pa[j]), inter);
                const float q = __fdiv_rn(inter, uni);    // IEEE f32 divide
                const u64 qh = (u64)__float_as_uint(q) << 32;
                const u64 mp = qh | (u32)(63 - t);
                if (mp > mbest[j]) mbest[j] = mp;
                atomicMax(&s_best[wv][t], qh | (u64)(0xFFFFFFFFu - pc[j]));
            }
        }
    }

    // per-prior decode info for the winner-row reconstruct path
    #pragma unroll
    for (int j = 0; j < KP; ++j) {
        const int   t_best = 63 - (int)(mbest[j] & 63u);
        const float q_best = __uint_as_float((u32)(mbest[j] >> 32));
        s_info[tid * KP + j] = (u8)(t_best | ((q_best < 0.5f) ? 0x80 : 0));
    }
    __syncthreads();

    // ---- block merge: publish partials (AGENT), mark local winners ----
    u32 winner_p = 0xFFFFFFFFu;
    if (tid < T_GT) {
        u64 m = s_best[0][tid];
        #pragma unroll
        for (int w = 1; w < 4; ++w) {
            const u64 v = s_best[w][tid];
            if (v > m) m = v;
        }
        __hip_atomic_store(&part[((size_t)b * NG + blockIdx.x) * T_GT + tid],
                           m, __ATOMIC_RELAXED, __HIP_MEMORY_SCOPE_AGENT);
        const u32 p = 0xFFFFFFFFu - (u32)(m & 0xFFFFFFFFull);
        // winner always originates from this block's priors, except the
        // untouched default {q=0,p=0} which is in range only for block 0
        if (p >= (u32)pbase && p < (u32)(pbase + NPRB)) {
            winner_p = p;
            s_skip[p - pbase] = 1;
        }
    }
    __syncthreads();

    // ---- bulk epilogue: cached coalesced stores for non-contended rows ----
    #pragma unroll
    for (int j = 0; j < KP; ++j) {
        const int p = tb * KP + j;
        if (p < P && !s_skip[tid * KP + j]) {
            const int   t_best = 63 - (int)(mbest[j] & 63u);
            const float q_best = __uint_as_float((u32)(mbest[j] >> 32));
            const int   lbl = (q_best < 0.5f) ? 0 : s_lbl[t_best];

            const float4 pr = prr[j];
            const float4 mb = s_gt[t_best];
            const float  bcx = (mb.x + mb.z) * 0.5f;
            const float  bcy = (mb.y + mb.w) * 0.5f;
            const float  bw  = mb.z - mb.x;
            const float  bh  = mb.w - mb.y;

            float4 loc;
            loc.x = (bcx - pr.x) / (0.1f * pr.z);
            loc.y = (bcy - pr.y) / (0.1f * pr.w);
            loc.z = logf(bw / pr.z) / 0.2f;
            loc.w = logf(bh / pr.w) / 0.2f;

            ((float4*)out_loc)[(size_t)b * P + p] = loc;
            out_lbl[(size_t)b * P + p] = (float)lbl;
        }
    }

    // ---- local-winner rows: AGENT stores (contended; LLC-ordered) ----
    if (winner_p != 0xFFFFFFFFu) {
        const u32 p = winner_p;
        const u8  info = s_info[p - pbase];
        const int t_best = info & 63;
        const int lbl = (info & 0x80) ? 0 : s_lbl[t_best];

        const float4 pr = priors[p];          // L1/L2-hot (block just read it)
        const float4 mb = s_gt[t_best];
        const float  bcx = (mb.x + mb.z) * 0.5f;
        const float  bcy = (mb.y + mb.w) * 0.5f;
        const float  bw  = mb.z - mb.x;
        const float  bh  = mb.w - mb.y;

        const float lx = (bcx - pr.x) / (0.1f * pr.z);
        const float ly = (bcy - pr.y) / (0.1f * pr.w);
        const float lz = logf(bw / pr.z) / 0.2f;
        const float lw = logf(bh / pr.w) / 0.2f;

        u64* rowp = (u64*)(out_loc + ((size_t)b * P + p) * 4);
        const u64 lo = ((u64)__float_as_uint(ly) << 32) | __float_as_uint(lx);
        const u64 hi = ((u64)__float_as_uint(lw) << 32) | __float_as_uint(lz);
        __hip_atomic_store(&rowp[0], lo, __ATOMIC_RELAXED, __HIP_MEMORY_SCOPE_AGENT);
        __hip_atomic_store(&rowp[1], hi, __ATOMIC_RELAXED, __HIP_MEMORY_SCOPE_AGENT);
        __hip_atomic_store((u32*)(out_lbl + (size_t)b * P + p),
                           __float_as_uint((float)lbl),
                           __ATOMIC_RELAXED, __HIP_MEMORY_SCOPE_AGENT);
    }

    // ---- hand-rolled release + last-block ticket (no fences, no wbl2) ----
    asm volatile("s_waitcnt vmcnt(0)" ::: "memory");  // all stores acked
    __syncthreads();
    if (tid == 0)
        s_rank = __hip_atomic_fetch_add(&cnt[b], 1u, __ATOMIC_RELAXED,
                                        __HIP_MEMORY_SCOPE_AGENT);
    __syncthreads();
    if (s_rank != (u32)(NG - 1)) return;

    // ---- finisher (last block of image b): reduce NG partials per t ----
    const int t = tid & 63;
    const int w = tid >> 6;
    const size_t base = (size_t)b * NG * T_GT + t;
    u64 m = 0;
    int g = w;
    for (; g + 12 < NG; g += 16) {      // 4 independent AGENT loads in flight
        const u64 a0 = __hip_atomic_load(&part[base + (size_t)g * T_GT],
                                         __ATOMIC_RELAXED, __HIP_MEMORY_SCOPE_AGENT);
        const u64 a1 = __hip_atomic_load(&part[base + (size_t)(g + 4) * T_GT],
                                         __ATOMIC_RELAXED, __HIP_MEMORY_SCOPE_AGENT);
        const u64 a2 = __hip_atomic_load(&part[base + (size_t)(g + 8) * T_GT],
                                         __ATOMIC_RELAXED, __HIP_MEMORY_SCOPE_AGENT);
        const u64 a3 = __hip_atomic_load(&part[base + (size_t)(g + 12) * T_GT],
                                         __ATOMIC_RELAXED, __HIP_MEMORY_SCOPE_AGENT);
        u64 x = a0 > a1 ? a0 : a1;
        const u64 y = a2 > a3 ? a2 : a3;
        if (y > x) x = y;
        if (x > m) m = x;
    }
    for (; g < NG; g += 4) {
        const u64 v = __hip_atomic_load(&part[base + (size_t)g * T_GT],
                                        __ATOMIC_RELAXED, __HIP_MEMORY_SCOPE_AGENT);
        if (v > m) m = v;
    }
    s_best[w][t] = m;                   // reuse (safe after syncthreads)
    __syncthreads();
    if (tid < T_GT) {
        m = s_best[0][t];
        #pragma unroll
        for (int i = 1; i < 4; ++i) {
            const u64 v = s_best[i][t];
            if (v > m) m = v;
        }
        s_p[t] = 0xFFFFFFFFu - (u32)(m & 0xFFFFFFFFull);
    }
    __syncthreads();
    if (tid >= T_GT) return;

    // matches[best_prior] = arange(T): numpy last-wins on duplicates
    const u32 p = s_p[tid];
    for (int u = tid + 1; u < T_GT; ++u)
        if (s_p[u] == p) return;

    const float4 pr = priors[p];        // input, read-only: never stale
    const float4 mb = s_gt[tid];
    const float  bcx = (mb.x + mb.z) * 0.5f;
    const float  bcy = (mb.y + mb.w) * 0.5f;
    const float  bw  = mb.z - mb.x;
    const float  bh  = mb.w - mb.y;

    const float lx = (bcx - pr.x) / (0.1f * pr.z);
    const float ly = (bcy - pr.y) / (0.1f * pr.w);
    const float lz = logf(bw / pr.z) / 0.2f;
    const float lw = logf(bh / pr.w) / 0.2f;

    u64* rowp = (u64*)(out_loc + ((size_t)b * P + p) * 4);
    const u64 lo = ((u64)__float_as_uint(ly) << 32) | __float_as_uint(lx);
    const u64 hi = ((u64)__float_as_uint(lw) << 32) | __float_as_uint(lz);
    __hip_atomic_store(&rowp[0], lo, __ATOMIC_RELAXED, __HIP_MEMORY_SCOPE_AGENT);
    __hip_atomic_store(&rowp[1], hi, __ATOMIC_RELAXED, __HIP_MEMORY_SCOPE_AGENT);
    __hip_atomic_store((u32*)(out_lbl + (size_t)b * P + p),
                       __float_as_uint((float)s_lbl[tid]),
                       __ATOMIC_RELAXED, __HIP_MEMORY_SCOPE_AGENT);
}

extern "C" void kernel_launch(void* const* d_in, const int* in_sizes, int n_in,
                              void* d_out, int out_size, void* d_ws, size_t ws_size,
                              hipStream_t stream) {
    const float4* priors    = (const float4*)d_in[0];   // (P, 4) f32
    const float4* gt_boxes  = (const float4*)d_in[1];   // (B, T, 4) f32
    const int*    gt_labels = (const int*)d_in[2];      // (B, T) i32

    const int P = in_sizes[0] / 4;
    const int B = in_sizes[2] / T_GT;

    float* out_loc = (float*)d_out;
    float* out_lbl = out_loc + (size_t)B * P * 4;

    const int NG = (P + NPRB - 1) / NPRB;              // blocks per image (196)
    u64* part = (u64*)d_ws;                            // (B, NG, 64) u64
    u32* cnt  = (u32*)((char*)d_ws + (size_t)B * NG * T_GT * sizeof(u64));

    // zero the B ticket counters only (64 bytes)
    hipMemsetAsync(cnt, 0, (size_t)B * sizeof(u32), stream);

    dim3 g(NG, B);
    fused_all<<<g, TPB, 0, stream>>>(priors, gt_boxes, gt_labels, part, cnt,
                                     out_loc, out_lbl, P, NG);
}